// Round 1
// baseline (321.618 us; speedup 1.0000x reference)
//
#include <hip/hip_runtime.h>

typedef __attribute__((ext_vector_type(8))) short short8;
typedef __attribute__((ext_vector_type(8))) int int8v;
typedef __attribute__((ext_vector_type(16))) float floatx16;
typedef __attribute__((ext_vector_type(4))) unsigned int uint4v;
typedef unsigned short ushort_t;
typedef unsigned int uint_t;
typedef unsigned char uchar_t;

#define NA   256
#define CIN  128
#define HFD  320
#define FMPX (HFD*HFD)
#define IMGD 1280

// ws layout (bytes):
//   [0, 1MB)              logits f32 (NA*1024)
//   [1MB, +294912)        w1b fp8  [tap][g][nt][c][lane64][32B]  (coalesced B-frag layout), scaled x64
//   [+294912, +311296)    w2r bf16 [32 krow][256 oc]
//   [2MB, 2MB+13107200)   fmT fp8  [320 y][320 x][128 c]
#define W1R_BYTE_OFF (1u<<20)
#define W2R_BYTE_OFF ((1u<<20) + 9*256*128)
#define FMT_BYTE_OFF (2u<<20)

#define SAPL_Q 5440               // A sub-plane bytes: 340 cells (10 rows x 34 cols) * 16
#define PSTR_Q 4112               // bytes per oc-octet plane of s_h: 8*32*16 + 16 pad

union V32 { int8v v; uint4v q[2]; };

__device__ __forceinline__ ushort_t f2bf(float v) {
    uint_t u = __float_as_uint(v);
    return (ushort_t)((u + 0x8000u) >> 16);
}
__device__ __forceinline__ uchar_t f2fp8(float v) {
    int r = __builtin_amdgcn_cvt_pk_fp8_f32(v, 0.0f, 0, false);
    return (uchar_t)(r & 0xff);
}

__global__ __launch_bounds__(256) void prep_misc(
    const float* __restrict__ W1, const float* __restrict__ W2,
    float* __restrict__ logits, float* __restrict__ out,
    uchar_t* __restrict__ w1b, ushort_t* __restrict__ w2r)
{
    const int b = blockIdx.x, t = threadIdx.x;
    if (b < 1024) {
        logits[b * 256 + t] = 0.0f;
    } else if (b < 1024 + 128) {
        int e = (b - 1024) * 256 + t;
        int oc = e >> 7, cin = e & 127;
        int g = oc >> 6, nt = (oc >> 5) & 1, lv = oc & 31;
        int c = cin >> 6, kh = (cin >> 5) & 1, j = cin & 31;
        #pragma unroll
        for (int tap = 0; tap < 9; ++tap) {
            int idx = (((((tap * 4 + g) * 2 + nt) * 2 + c) * 64) + kh * 32 + lv) * 32 + j;
            w1b[idx] = f2fp8(W1[(oc * 128 + cin) * 9 + tap] * 64.0f);
        }
    } else {
        #pragma unroll
        for (int i = 0; i < 32; ++i) {
            int e = i * 256 + t;
            int nrow = e >> 8, oc = e & 255;
            w2r[nrow * 256 + oc] = f2bf(nrow < 9 ? W2[oc * 9 + nrow] : 0.0f);
        }
        if (t == 0) out[0] = 0.0f;
    }
}

// fm f32 [c][y][x] -> fmT fp8 [y][x][c]
__global__ __launch_bounds__(256) void prep_transpose(
    const float* __restrict__ fm, uchar_t* __restrict__ fmT)
{
    __shared__ uchar_t s[32 * 144];
    const int t = threadIdx.x;
    const int y = blockIdx.y, x0b = blockIdx.x * 32;
    #pragma unroll
    for (int i = 0; i < 16; ++i) {
        int e = t + 256 * i;
        int c = e >> 5, xo = e & 31;
        s[xo * 144 + c] = f2fp8(fm[(size_t)c * FMPX + y * HFD + x0b + xo]);
    }
    __syncthreads();
    {
        int xo = t >> 3, cg = t & 7;
        uint4v v = *(const uint4v*)&s[xo * 144 + cg * 16];
        *(uint4v*)&fmT[((size_t)(y * HFD + x0b + xo)) * 128 + cg * 16] = v;
    }
}

// Block = (anchor, 8-row quarter, 64-oc group); grid 4096, XCD-swizzled (all 16 blocks
// of an anchor on one XCD for fmT L2 locality).
// Occupancy design: LDS = 32896 (SA 21760 unioned with s_h 32896 + s_log), acc[2][2]=64
// regs/wave -> target 4 blocks/CU (16 waves) vs previous 2 (8 waves).
// B operand is NOT staged in LDS: w1b is pre-permuted so a B-frag = one coalesced
// 2048-B wave read (lane*32), served from L1/L2 (288 KB total, hot everywhere).
// MFMA accumulation order (c, kx, ky) identical to previous kernel -> bit-exact conv.
__global__ __launch_bounds__(256, 4) void conv_mfma_kernel(
    const int* __restrict__ anchors, const uchar_t* __restrict__ fmT,
    const uchar_t* __restrict__ w1b, const ushort_t* __restrict__ w2r,
    const float* __restrict__ b1, float* __restrict__ logits)
{
    const int id   = blockIdx.x;
    const int xcd  = id & 7, sid = id >> 3;
    const int n    = xcd * 32 + (sid >> 4);
    const int rem  = sid & 15;
    const int q    = rem >> 2;
    const int g    = rem & 3;

    const int t    = threadIdx.x;
    const int w    = t >> 6;
    const int lane = t & 63;
    const int l31  = lane & 31;
    const int kh   = lane >> 5;

    const int x0 = anchors[n * 4 + 0];
    const int y0 = anchors[n * 4 + 2];
    const int r0 = q * 8;

    __shared__ __align__(16) char smem[8 * PSTR_Q];   // 32896 B: s_a(21760) / s_h / s_log union
    char* s_a = smem;

    // zero col pads (cols 0 & 33 of 10 rows, 4 sub-planes) — persist across both chunks
    if (t < 80) {
        int sub = t & 3, k = t >> 2;
        int pr = k >> 1, col = (k & 1) * 33;
        uint4v z = {0u, 0u, 0u, 0u};
        *(uint4v*)(s_a + sub * SAPL_Q + (pr * 34 + col) * 16) = z;
    }

    floatx16 acc[2][2];
    #pragma unroll
    for (int mt = 0; mt < 2; ++mt)
        #pragma unroll
        for (int nt = 0; nt < 2; ++nt)
            #pragma unroll
            for (int r = 0; r < 16; ++r) acc[mt][nt][r] = 0.0f;

    for (int c = 0; c < 2; ++c) {
        __syncthreads();   // c0: pad zeros visible; c1: all waves done reading chunk0
        // ---- stage A: 10 rows x 32 real cols x 4 subs = 1280 uint4 units (5 iters) ----
        // invalid halo rows (cr outside [0,32)) are written as zeros (conv SAME pad)
        #pragma unroll
        for (int j = 0; j < 5; ++j) {
            int u = t + 256 * j;
            int pr = u >> 7, rr = u & 127;
            int cell = rr >> 2, sub = rr & 3;
            int cr = r0 + pr - 1;
            uint4v v = {0u, 0u, 0u, 0u};
            if ((unsigned)cr < 32u)
                v = *(const uint4v*)&fmT[((size_t)((y0 + cr) * HFD + x0 + cell)) * 128 + c * 64 + sub * 16];
            *(uint4v*)(s_a + sub * SAPL_Q + (pr * 34 + cell + 1) * 16) = v;
        }
        __syncthreads();
        // ---- MFMA: per (kx,ky): 2 A-frags (LDS) + 2 B-frags (global, coalesced) -> 4 MFMAs ----
        #pragma unroll
        for (int kx = 0; kx < 3; ++kx) {
            #pragma unroll
            for (int ky = 0; ky < 3; ++ky) {
                const int tap = ky * 3 + kx;
                V32 b8[2];
                #pragma unroll
                for (int nt = 0; nt < 2; ++nt) {
                    const uchar_t* bp = w1b + ((((tap * 4 + g) * 2 + nt) * 2 + c) << 11) + lane * 32;
                    b8[nt].q[0] = *(const uint4v*)(bp);
                    b8[nt].q[1] = *(const uint4v*)(bp + 16);
                }
                V32 a2[2];
                #pragma unroll
                for (int f = 0; f < 2; ++f) {
                    int cell = (2 * w + ky + f) * 34 + l31 + kx;
                    a2[f].q[0] = *(const uint4v*)(s_a + (2 * kh)     * SAPL_Q + cell * 16);
                    a2[f].q[1] = *(const uint4v*)(s_a + (2 * kh + 1) * SAPL_Q + cell * 16);
                }
                #pragma unroll
                for (int mt = 0; mt < 2; ++mt) {
                    acc[mt][0] = __builtin_amdgcn_mfma_scale_f32_32x32x64_f8f6f4(
                        a2[mt].v, b8[0].v, acc[mt][0], 0, 0, 0, 127, 0, 127);
                    acc[mt][1] = __builtin_amdgcn_mfma_scale_f32_32x32x64_f8f6f4(
                        a2[mt].v, b8[1].v, acc[mt][1], 0, 0, 0, 127, 0, 127);
                }
            }
        }
    }

    // ---- epilogue: h = acc/64 + b1, relu -> s_h (bf16, 8 planes of 8 oc) ----
    __syncthreads();
    #pragma unroll
    for (int nt = 0; nt < 2; ++nt) {
        float bias = b1[g * 64 + nt * 32 + l31];
        int plane = nt * 4 + (l31 >> 3);
        #pragma unroll
        for (int mt = 0; mt < 2; ++mt) {
            int lr = 2 * w + mt;
            #pragma unroll
            for (int reg = 0; reg < 16; ++reg) {
                int col = (reg & 3) + 8 * (reg >> 2) + 4 * kh;   // C layout: m = crop col
                float hv = fmaxf(fmaf(acc[mt][nt][reg], 0.015625f, bias), 0.0f);
                *(ushort_t*)(smem + plane * PSTR_Q + ((lr * 32 + col) * 8 + (l31 & 7)) * 2) = f2bf(hv);
            }
        }
    }
    __syncthreads();

    // ---- v_tap = h @ W2^T (bf16, K=64 oc over 4 x K16) ----
    floatx16 vacc[2];
    #pragma unroll
    for (int mt = 0; mt < 2; ++mt)
        #pragma unroll
        for (int r = 0; r < 16; ++r) vacc[mt][r] = 0.0f;
    #pragma unroll
    for (int ks = 0; ks < 4; ++ks) {
        short8 bw = *(const short8*)&w2r[l31 * 256 + g * 64 + ks * 16 + kh * 8];
        #pragma unroll
        for (int mt = 0; mt < 2; ++mt) {
            short8 ah = *(const short8*)(smem + (ks * 2 + kh) * PSTR_Q + ((2 * w + mt) * 32 + l31) * 16);
            vacc[mt] = __builtin_amdgcn_mfma_f32_32x32x16_bf16(ah, bw, vacc[mt], 0, 0, 0);
        }
    }

    // ---- scatter v_tap into 10x32 tile (s_h now dead -> union), then global atomics ----
    __syncthreads();
    float* s_log = (float*)smem;
    for (int i = t; i < 320; i += 256) s_log[i] = 0.0f;
    __syncthreads();
    if (l31 < 9) {
        int ky = l31 / 3, kx = l31 - ky * 3;
        #pragma unroll
        for (int mt = 0; mt < 2; ++mt) {
            int outr = 2 * w + mt + 2 - ky;       // tile row; R = r0 + outr - 1
            #pragma unroll
            for (int reg = 0; reg < 16; ++reg) {
                int col  = (reg & 3) + 8 * (reg >> 2) + 4 * kh;
                int outc = col + 1 - kx;
                if (outc >= 0 && outc < 32)
                    atomicAdd(&s_log[outr * 32 + outc], vacc[mt][reg]);
            }
        }
    }
    __syncthreads();
    for (int i = t; i < 320; i += 256) {
        int outr = i >> 5, outc = i & 31;
        int R = r0 + outr - 1;
        if ((unsigned)R < 32u)
            atomicAdd(&logits[n * 1024 + R * 32 + outc], s_log[i]);
    }
}

__global__ __launch_bounds__(256) void bce_reduce_kernel(
    const float* __restrict__ logits, const int* __restrict__ seg,
    const int* __restrict__ anchors, const int* __restrict__ labels,
    const int* __restrict__ base_classes, const float* __restrict__ b2,
    float* __restrict__ out)
{
    const int n = blockIdx.x;
    const int t = threadIdx.x;
    const int y0 = anchors[n * 4 + 2];
    const int x0 = anchors[n * 4 + 0];
    const int tgt_cls = base_classes[labels[n]];
    const float bias2 = b2[0];

    float lsum = 0.0f;
    #pragma unroll
    for (int r = 0; r < 4; ++r) {
        int p = t + r * 256;
        int i = p >> 5, j = p & 31;
        float l = logits[n * 1024 + p] + bias2;
        int sv = seg[(size_t)(4 * (y0 + i)) * IMGD + 4 * (x0 + j)];
        float tgt = (sv == tgt_cls) ? 1.0f : 0.0f;
        lsum += fmaxf(l, 0.0f) - l * tgt + log1pf(expf(-fabsf(l)));
    }
    #pragma unroll
    for (int off = 32; off > 0; off >>= 1) lsum += __shfl_down(lsum, off, 64);
    __shared__ float s[4];
    if ((t & 63) == 0) s[t >> 6] = lsum;
    __syncthreads();
    if (t == 0) {
        float tot = s[0] + s[1] + s[2] + s[3];
        const float scale = 1.0f / (1024.0f * (256.0f + 1e-10f));
        atomicAdd(out, tot * scale);
    }
}

extern "C" void kernel_launch(void* const* d_in, const int* in_sizes, int n_in,
                              void* d_out, int out_size, void* d_ws, size_t ws_size,
                              hipStream_t stream) {
    const float* fm           = (const float*)d_in[0];
    const int*   seg          = (const int*)d_in[1];
    const int*   anchors      = (const int*)d_in[2];
    const int*   labels       = (const int*)d_in[3];
    const int*   base_classes = (const int*)d_in[4];
    const float* W1           = (const float*)d_in[5];
    const float* b1           = (const float*)d_in[6];
    const float* W2           = (const float*)d_in[7];
    const float* b2           = (const float*)d_in[8];
    float* out = (float*)d_out;

    float*    logits = (float*)d_ws;
    uchar_t*  w1b    = (uchar_t*)((char*)d_ws + W1R_BYTE_OFF);
    ushort_t* w2r    = (ushort_t*)((char*)d_ws + W2R_BYTE_OFF);
    uchar_t*  fmT    = (uchar_t*)((char*)d_ws + FMT_BYTE_OFF);

    prep_misc<<<1024 + 128 + 1, 256, 0, stream>>>(W1, W2, logits, out, w1b, w2r);
    prep_transpose<<<dim3(10, 320), 256, 0, stream>>>(fm, fmT);
    conv_mfma_kernel<<<4096, 256, 0, stream>>>(anchors, fmT, w1b, w2r, b1, logits);
    bce_reduce_kernel<<<NA, 256, 0, stream>>>(logits, seg, anchors, labels, base_classes, b2, out);
}

// Round 2
// 295.009 us; speedup vs baseline: 1.0902x; 1.0902x over previous
//
#include <hip/hip_runtime.h>

typedef __attribute__((ext_vector_type(8))) short short8;
typedef __attribute__((ext_vector_type(8))) int int8v;
typedef __attribute__((ext_vector_type(16))) float floatx16;
typedef __attribute__((ext_vector_type(4))) unsigned int uint4v;
typedef unsigned short ushort_t;
typedef unsigned int uint_t;
typedef unsigned char uchar_t;

#define NA   256
#define CIN  128
#define HFD  320
#define FMPX (HFD*HFD)
#define IMGD 1280

// ws layout (bytes):
//   [0, 1MB)              logits f32 (NA*1024)
//   [1MB, +294912)        w1b fp8  [tap][g][nt][c][lane64][32B]  (coalesced B-frag layout), scaled x64
//   [+294912, +311296)    w2r bf16 [32 krow][256 oc]
//   [2MB, 2MB+13107200)   fmT fp8  [320 y][320 x][128 c]
#define W1R_BYTE_OFF (1u<<20)
#define W2R_BYTE_OFF ((1u<<20) + 9*256*128)
#define FMT_BYTE_OFF (2u<<20)

#define SAPL_Q 5440               // A sub-plane bytes: 340 cells (10 rows x 34 cols) * 16
#define PSTR_Q 4112               // bytes per oc-octet plane of s_h: 8*32*16 + 16 pad

union V32 { int8v v; uint4v q[2]; };

__device__ __forceinline__ ushort_t f2bf(float v) {
    uint_t u = __float_as_uint(v);
    return (ushort_t)((u + 0x8000u) >> 16);
}
__device__ __forceinline__ uchar_t f2fp8(float v) {
    int r = __builtin_amdgcn_cvt_pk_fp8_f32(v, 0.0f, 0, false);
    return (uchar_t)(r & 0xff);
}

__global__ __launch_bounds__(256) void prep_misc(
    const float* __restrict__ W1, const float* __restrict__ W2,
    float* __restrict__ logits, float* __restrict__ out,
    uchar_t* __restrict__ w1b, ushort_t* __restrict__ w2r)
{
    const int b = blockIdx.x, t = threadIdx.x;
    if (b < 1024) {
        logits[b * 256 + t] = 0.0f;
    } else if (b < 1024 + 128) {
        int e = (b - 1024) * 256 + t;
        int oc = e >> 7, cin = e & 127;
        int g = oc >> 6, nt = (oc >> 5) & 1, lv = oc & 31;
        int c = cin >> 6, kh = (cin >> 5) & 1, j = cin & 31;
        #pragma unroll
        for (int tap = 0; tap < 9; ++tap) {
            int idx = (((((tap * 4 + g) * 2 + nt) * 2 + c) * 64) + kh * 32 + lv) * 32 + j;
            w1b[idx] = f2fp8(W1[(oc * 128 + cin) * 9 + tap] * 64.0f);
        }
    } else {
        #pragma unroll
        for (int i = 0; i < 32; ++i) {
            int e = i * 256 + t;
            int nrow = e >> 8, oc = e & 255;
            w2r[nrow * 256 + oc] = f2bf(nrow < 9 ? W2[oc * 9 + nrow] : 0.0f);
        }
        if (t == 0) out[0] = 0.0f;
    }
}

// fm f32 [c][y][x] -> fmT fp8 [y][x][c]
__global__ __launch_bounds__(256) void prep_transpose(
    const float* __restrict__ fm, uchar_t* __restrict__ fmT)
{
    __shared__ uchar_t s[32 * 144];
    const int t = threadIdx.x;
    const int y = blockIdx.y, x0b = blockIdx.x * 32;
    #pragma unroll
    for (int i = 0; i < 16; ++i) {
        int e = t + 256 * i;
        int c = e >> 5, xo = e & 31;
        s[xo * 144 + c] = f2fp8(fm[(size_t)c * FMPX + y * HFD + x0b + xo]);
    }
    __syncthreads();
    {
        int xo = t >> 3, cg = t & 7;
        uint4v v = *(const uint4v*)&s[xo * 144 + cg * 16];
        *(uint4v*)&fmT[((size_t)(y * HFD + x0b + xo)) * 128 + cg * 16] = v;
    }
}

// Block = (anchor, 8-row quarter, 64-oc group); grid 4096, XCD-swizzled (all 16 blocks
// of an anchor on one XCD for fmT L2 locality).
// Occupancy design: LDS = 32896 (4 blocks/CU worth), acc[2][2]=64 regs/wave.
// __launch_bounds__(256,3): reg cap 170 -> 3 blocks/CU (12 waves). (256,4)'s 128-reg cap
// SPILLED (R1: 450 MB scratch writes, VGPR_Count=64, 41% HBM) -- do not tighten again.
// B operand is NOT staged in LDS: w1b is pre-permuted so a B-frag = one coalesced
// 2048-B wave read (lane*32), served from L1/L2 (288 KB total, hot everywhere).
// MFMA accumulation order (c, kx, ky) identical to previous kernel -> bit-exact conv.
__global__ __launch_bounds__(256, 3) void conv_mfma_kernel(
    const int* __restrict__ anchors, const uchar_t* __restrict__ fmT,
    const uchar_t* __restrict__ w1b, const ushort_t* __restrict__ w2r,
    const float* __restrict__ b1, float* __restrict__ logits)
{
    const int id   = blockIdx.x;
    const int xcd  = id & 7, sid = id >> 3;
    const int n    = xcd * 32 + (sid >> 4);
    const int rem  = sid & 15;
    const int q    = rem >> 2;
    const int g    = rem & 3;

    const int t    = threadIdx.x;
    const int w    = t >> 6;
    const int lane = t & 63;
    const int l31  = lane & 31;
    const int kh   = lane >> 5;

    const int x0 = anchors[n * 4 + 0];
    const int y0 = anchors[n * 4 + 2];
    const int r0 = q * 8;

    __shared__ __align__(16) char smem[8 * PSTR_Q];   // 32896 B: s_a(21760) / s_h / s_log union
    char* s_a = smem;

    // zero col pads (cols 0 & 33 of 10 rows, 4 sub-planes) — persist across both chunks
    if (t < 80) {
        int sub = t & 3, k = t >> 2;
        int pr = k >> 1, col = (k & 1) * 33;
        uint4v z = {0u, 0u, 0u, 0u};
        *(uint4v*)(s_a + sub * SAPL_Q + (pr * 34 + col) * 16) = z;
    }

    floatx16 acc[2][2];
    #pragma unroll
    for (int mt = 0; mt < 2; ++mt)
        #pragma unroll
        for (int nt = 0; nt < 2; ++nt)
            #pragma unroll
            for (int r = 0; r < 16; ++r) acc[mt][nt][r] = 0.0f;

    for (int c = 0; c < 2; ++c) {
        __syncthreads();   // c0: pad zeros visible; c1: all waves done reading chunk0
        // ---- stage A: 10 rows x 32 real cols x 4 subs = 1280 uint4 units (5 iters) ----
        // invalid halo rows (cr outside [0,32)) are written as zeros (conv SAME pad)
        #pragma unroll
        for (int j = 0; j < 5; ++j) {
            int u = t + 256 * j;
            int pr = u >> 7, rr = u & 127;
            int cell = rr >> 2, sub = rr & 3;
            int cr = r0 + pr - 1;
            uint4v v = {0u, 0u, 0u, 0u};
            if ((unsigned)cr < 32u)
                v = *(const uint4v*)&fmT[((size_t)((y0 + cr) * HFD + x0 + cell)) * 128 + c * 64 + sub * 16];
            *(uint4v*)(s_a + sub * SAPL_Q + (pr * 34 + cell + 1) * 16) = v;
        }
        __syncthreads();
        // ---- MFMA: per (kx,ky): 2 A-frags (LDS) + 2 B-frags (global, coalesced) -> 4 MFMAs ----
        #pragma unroll
        for (int kx = 0; kx < 3; ++kx) {
            #pragma unroll
            for (int ky = 0; ky < 3; ++ky) {
                const int tap = ky * 3 + kx;
                V32 b8[2];
                #pragma unroll
                for (int nt = 0; nt < 2; ++nt) {
                    const uchar_t* bp = w1b + ((((tap * 4 + g) * 2 + nt) * 2 + c) << 11) + lane * 32;
                    b8[nt].q[0] = *(const uint4v*)(bp);
                    b8[nt].q[1] = *(const uint4v*)(bp + 16);
                }
                V32 a2[2];
                #pragma unroll
                for (int f = 0; f < 2; ++f) {
                    int cell = (2 * w + ky + f) * 34 + l31 + kx;
                    a2[f].q[0] = *(const uint4v*)(s_a + (2 * kh)     * SAPL_Q + cell * 16);
                    a2[f].q[1] = *(const uint4v*)(s_a + (2 * kh + 1) * SAPL_Q + cell * 16);
                }
                #pragma unroll
                for (int mt = 0; mt < 2; ++mt) {
                    acc[mt][0] = __builtin_amdgcn_mfma_scale_f32_32x32x64_f8f6f4(
                        a2[mt].v, b8[0].v, acc[mt][0], 0, 0, 0, 127, 0, 127);
                    acc[mt][1] = __builtin_amdgcn_mfma_scale_f32_32x32x64_f8f6f4(
                        a2[mt].v, b8[1].v, acc[mt][1], 0, 0, 0, 127, 0, 127);
                }
            }
        }
    }

    // ---- epilogue: h = acc/64 + b1, relu -> s_h (bf16, 8 planes of 8 oc) ----
    __syncthreads();
    #pragma unroll
    for (int nt = 0; nt < 2; ++nt) {
        float bias = b1[g * 64 + nt * 32 + l31];
        int plane = nt * 4 + (l31 >> 3);
        #pragma unroll
        for (int mt = 0; mt < 2; ++mt) {
            int lr = 2 * w + mt;
            #pragma unroll
            for (int reg = 0; reg < 16; ++reg) {
                int col = (reg & 3) + 8 * (reg >> 2) + 4 * kh;   // C layout: m = crop col
                float hv = fmaxf(fmaf(acc[mt][nt][reg], 0.015625f, bias), 0.0f);
                *(ushort_t*)(smem + plane * PSTR_Q + ((lr * 32 + col) * 8 + (l31 & 7)) * 2) = f2bf(hv);
            }
        }
    }
    __syncthreads();

    // ---- v_tap = h @ W2^T (bf16, K=64 oc over 4 x K16) ----
    floatx16 vacc[2];
    #pragma unroll
    for (int mt = 0; mt < 2; ++mt)
        #pragma unroll
        for (int r = 0; r < 16; ++r) vacc[mt][r] = 0.0f;
    #pragma unroll
    for (int ks = 0; ks < 4; ++ks) {
        short8 bw = *(const short8*)&w2r[l31 * 256 + g * 64 + ks * 16 + kh * 8];
        #pragma unroll
        for (int mt = 0; mt < 2; ++mt) {
            short8 ah = *(const short8*)(smem + (ks * 2 + kh) * PSTR_Q + ((2 * w + mt) * 32 + l31) * 16);
            vacc[mt] = __builtin_amdgcn_mfma_f32_32x32x16_bf16(ah, bw, vacc[mt], 0, 0, 0);
        }
    }

    // ---- scatter v_tap into 10x32 tile (s_h now dead -> union), then global atomics ----
    __syncthreads();
    float* s_log = (float*)smem;
    for (int i = t; i < 320; i += 256) s_log[i] = 0.0f;
    __syncthreads();
    if (l31 < 9) {
        int ky = l31 / 3, kx = l31 - ky * 3;
        #pragma unroll
        for (int mt = 0; mt < 2; ++mt) {
            int outr = 2 * w + mt + 2 - ky;       // tile row; R = r0 + outr - 1
            #pragma unroll
            for (int reg = 0; reg < 16; ++reg) {
                int col  = (reg & 3) + 8 * (reg >> 2) + 4 * kh;
                int outc = col + 1 - kx;
                if (outc >= 0 && outc < 32)
                    atomicAdd(&s_log[outr * 32 + outc], vacc[mt][reg]);
            }
        }
    }
    __syncthreads();
    for (int i = t; i < 320; i += 256) {
        int outr = i >> 5, outc = i & 31;
        int R = r0 + outr - 1;
        if ((unsigned)R < 32u)
            atomicAdd(&logits[n * 1024 + R * 32 + outc], s_log[i]);
    }
}

__global__ __launch_bounds__(256) void bce_reduce_kernel(
    const float* __restrict__ logits, const int* __restrict__ seg,
    const int* __restrict__ anchors, const int* __restrict__ labels,
    const int* __restrict__ base_classes, const float* __restrict__ b2,
    float* __restrict__ out)
{
    const int n = blockIdx.x;
    const int t = threadIdx.x;
    const int y0 = anchors[n * 4 + 2];
    const int x0 = anchors[n * 4 + 0];
    const int tgt_cls = base_classes[labels[n]];
    const float bias2 = b2[0];

    float lsum = 0.0f;
    #pragma unroll
    for (int r = 0; r < 4; ++r) {
        int p = t + r * 256;
        int i = p >> 5, j = p & 31;
        float l = logits[n * 1024 + p] + bias2;
        int sv = seg[(size_t)(4 * (y0 + i)) * IMGD + 4 * (x0 + j)];
        float tgt = (sv == tgt_cls) ? 1.0f : 0.0f;
        lsum += fmaxf(l, 0.0f) - l * tgt + log1pf(expf(-fabsf(l)));
    }
    #pragma unroll
    for (int off = 32; off > 0; off >>= 1) lsum += __shfl_down(lsum, off, 64);
    __shared__ float s[4];
    if ((t & 63) == 0) s[t >> 6] = lsum;
    __syncthreads();
    if (t == 0) {
        float tot = s[0] + s[1] + s[2] + s[3];
        const float scale = 1.0f / (1024.0f * (256.0f + 1e-10f));
        atomicAdd(out, tot * scale);
    }
}

extern "C" void kernel_launch(void* const* d_in, const int* in_sizes, int n_in,
                              void* d_out, int out_size, void* d_ws, size_t ws_size,
                              hipStream_t stream) {
    const float* fm           = (const float*)d_in[0];
    const int*   seg          = (const int*)d_in[1];
    const int*   anchors      = (const int*)d_in[2];
    const int*   labels       = (const int*)d_in[3];
    const int*   base_classes = (const int*)d_in[4];
    const float* W1           = (const float*)d_in[5];
    const float* b1           = (const float*)d_in[6];
    const float* W2           = (const float*)d_in[7];
    const float* b2           = (const float*)d_in[8];
    float* out = (float*)d_out;

    float*    logits = (float*)d_ws;
    uchar_t*  w1b    = (uchar_t*)((char*)d_ws + W1R_BYTE_OFF);
    ushort_t* w2r    = (ushort_t*)((char*)d_ws + W2R_BYTE_OFF);
    uchar_t*  fmT    = (uchar_t*)((char*)d_ws + FMT_BYTE_OFF);

    prep_misc<<<1024 + 128 + 1, 256, 0, stream>>>(W1, W2, logits, out, w1b, w2r);
    prep_transpose<<<dim3(10, 320), 256, 0, stream>>>(fm, fmT);
    conv_mfma_kernel<<<4096, 256, 0, stream>>>(anchors, fmT, w1b, w2r, b1, logits);
    bce_reduce_kernel<<<NA, 256, 0, stream>>>(logits, seg, anchors, labels, base_classes, b2, out);
}

// Round 3
// 231.619 us; speedup vs baseline: 1.3886x; 1.2737x over previous
//
#include <hip/hip_runtime.h>

typedef __attribute__((ext_vector_type(8))) short short8;
typedef __attribute__((ext_vector_type(8))) int int8v;
typedef __attribute__((ext_vector_type(16))) float floatx16;
typedef __attribute__((ext_vector_type(4))) unsigned int uint4v;
typedef unsigned short ushort_t;
typedef unsigned int uint_t;
typedef unsigned char uchar_t;

#define NA   256
#define CIN  128
#define HFD  320
#define FMPX (HFD*HFD)
#define IMGD 1280

// ws layout (bytes):
//   [0, 1MB)              logits f32 (NA*1024)
//   [1MB, +294912)        w1b fp8  [tap][g][nt][c][lane64][32B]  (coalesced B-frag layout), scaled x64
//   [+294912, +311296)    w2r bf16 [32 krow][256 oc]
//   [2MB, 2MB+13107200)   fmT fp8  [320 y][320 x][128 c]
#define W1R_BYTE_OFF (1u<<20)
#define W2R_BYTE_OFF ((1u<<20) + 9*256*128)
#define FMT_BYTE_OFF (2u<<20)

#define SAPL_Q 5440               // A sub-plane bytes: 340 cells (10 rows x 34 cols) * 16
#define PSTR_Q 4112               // bytes per oc-octet plane of s_h: 8*32*16 + 16 pad

union V32 { int8v v; uint4v q[2]; };

__device__ __forceinline__ ushort_t f2bf(float v) {
    uint_t u = __float_as_uint(v);
    return (ushort_t)((u + 0x8000u) >> 16);
}
__device__ __forceinline__ uchar_t f2fp8(float v) {
    int r = __builtin_amdgcn_cvt_pk_fp8_f32(v, 0.0f, 0, false);
    return (uchar_t)(r & 0xff);
}

__global__ __launch_bounds__(256) void prep_misc(
    const float* __restrict__ W1, const float* __restrict__ W2,
    float* __restrict__ logits, float* __restrict__ out,
    uchar_t* __restrict__ w1b, ushort_t* __restrict__ w2r)
{
    const int b = blockIdx.x, t = threadIdx.x;
    if (b < 1024) {
        logits[b * 256 + t] = 0.0f;
    } else if (b < 1024 + 128) {
        int e = (b - 1024) * 256 + t;
        int oc = e >> 7, cin = e & 127;
        int g = oc >> 6, nt = (oc >> 5) & 1, lv = oc & 31;
        int c = cin >> 6, kh = (cin >> 5) & 1, j = cin & 31;
        #pragma unroll
        for (int tap = 0; tap < 9; ++tap) {
            int idx = (((((tap * 4 + g) * 2 + nt) * 2 + c) * 64) + kh * 32 + lv) * 32 + j;
            w1b[idx] = f2fp8(W1[(oc * 128 + cin) * 9 + tap] * 64.0f);
        }
    } else {
        #pragma unroll
        for (int i = 0; i < 32; ++i) {
            int e = i * 256 + t;
            int nrow = e >> 8, oc = e & 255;
            w2r[nrow * 256 + oc] = f2bf(nrow < 9 ? W2[oc * 9 + nrow] : 0.0f);
        }
        if (t == 0) out[0] = 0.0f;
    }
}

// fm f32 [c][y][x] -> fmT fp8 [y][x][c]
__global__ __launch_bounds__(256) void prep_transpose(
    const float* __restrict__ fm, uchar_t* __restrict__ fmT)
{
    __shared__ uchar_t s[32 * 144];
    const int t = threadIdx.x;
    const int y = blockIdx.y, x0b = blockIdx.x * 32;
    #pragma unroll
    for (int i = 0; i < 16; ++i) {
        int e = t + 256 * i;
        int c = e >> 5, xo = e & 31;
        s[xo * 144 + c] = f2fp8(fm[(size_t)c * FMPX + y * HFD + x0b + xo]);
    }
    __syncthreads();
    {
        int xo = t >> 3, cg = t & 7;
        uint4v v = *(const uint4v*)&s[xo * 144 + cg * 16];
        *(uint4v*)&fmT[((size_t)(y * HFD + x0b + xo)) * 128 + cg * 16] = v;
    }
}

// Block = (anchor, 8-row quarter, 64-oc group); grid 4096, XCD-swizzled (all 16 blocks
// of an anchor on one XCD for fmT L2 locality).
// Occupancy design: LDS = 32896, acc[2][2]=64 regs/wave, launch_bounds(256,3) -> 3 blocks/CU.
// SPILL HISTORY (do not regress): fully-unrolled kx/ky loops made the scheduler hoist all
// 36 B global loads (288 regs) and spill at ANY cap (R1: 450 MB scratch @cap128; R2: 253 MB
// @cap170). Fix: tap loop is ROLLED (#pragma unroll 1) with a manual 1-deep B prefetch
// ping (bcur/bnxt, explicit copy -- no runtime-indexed reg arrays). Live set ~130 regs by
// construction. Accumulation order (c, kx, ky) preserved exactly: s -> kx=s/3, ky=s%3.
// B operand is NOT staged in LDS: w1b is pre-permuted so a B-frag = one coalesced
// 2048-B wave read (lane*32), served from L1/L2 (288 KB total, hot everywhere).
__global__ __launch_bounds__(256, 3) void conv_mfma_kernel(
    const int* __restrict__ anchors, const uchar_t* __restrict__ fmT,
    const uchar_t* __restrict__ w1b, const ushort_t* __restrict__ w2r,
    const float* __restrict__ b1, float* __restrict__ logits)
{
    const int id   = blockIdx.x;
    const int xcd  = id & 7, sid = id >> 3;
    const int n    = xcd * 32 + (sid >> 4);
    const int rem  = sid & 15;
    const int q    = rem >> 2;
    const int g    = rem & 3;

    const int t    = threadIdx.x;
    const int w    = t >> 6;
    const int lane = t & 63;
    const int l31  = lane & 31;
    const int kh   = lane >> 5;

    const int x0 = anchors[n * 4 + 0];
    const int y0 = anchors[n * 4 + 2];
    const int r0 = q * 8;

    __shared__ __align__(16) char smem[8 * PSTR_Q];   // 32896 B: s_a(21760) / s_h / s_log union
    char* s_a = smem;

    // zero col pads (cols 0 & 33 of 10 rows, 4 sub-planes) — persist across both chunks
    if (t < 80) {
        int sub = t & 3, k = t >> 2;
        int pr = k >> 1, col = (k & 1) * 33;
        uint4v z = {0u, 0u, 0u, 0u};
        *(uint4v*)(s_a + sub * SAPL_Q + (pr * 34 + col) * 16) = z;
    }

    floatx16 acc[2][2];
    #pragma unroll
    for (int mt = 0; mt < 2; ++mt)
        #pragma unroll
        for (int nt = 0; nt < 2; ++nt)
            #pragma unroll
            for (int r = 0; r < 16; ++r) acc[mt][nt][r] = 0.0f;

    // B-fragment loader: tap in [0,9), cc = cin chunk
    auto loadB = [&](int tap, int cc, V32* b) {
        #pragma unroll
        for (int nt = 0; nt < 2; ++nt) {
            const uchar_t* bp = w1b + ((((tap * 4 + g) * 2 + nt) * 2 + cc) << 11) + lane * 32;
            b[nt].q[0] = *(const uint4v*)(bp);
            b[nt].q[1] = *(const uint4v*)(bp + 16);
        }
    };

    V32 bcur[2], bnxt[2];
    loadB(0, 0, bcur);    // tap for s=0 (kx=0,ky=0) of chunk 0

    for (int c = 0; c < 2; ++c) {
        __syncthreads();   // c0: pad zeros visible; c1: all waves done reading chunk0
        // ---- stage A: 10 rows x 32 real cols x 4 subs = 1280 uint4 units (5 iters) ----
        // invalid halo rows (cr outside [0,32)) are written as zeros (conv SAME pad)
        #pragma unroll
        for (int j = 0; j < 5; ++j) {
            int u = t + 256 * j;
            int pr = u >> 7, rr = u & 127;
            int cell = rr >> 2, sub = rr & 3;
            int cr = r0 + pr - 1;
            uint4v v = {0u, 0u, 0u, 0u};
            if ((unsigned)cr < 32u)
                v = *(const uint4v*)&fmT[((size_t)((y0 + cr) * HFD + x0 + cell)) * 128 + c * 64 + sub * 16];
            *(uint4v*)(s_a + sub * SAPL_Q + (pr * 34 + cell + 1) * 16) = v;
        }
        __syncthreads();
        // ---- MFMA: rolled tap loop, 1-deep B prefetch; per s: 2 A-frags (LDS) + 4 MFMAs ----
        #pragma unroll 1
        for (int s = 0; s < 9; ++s) {
            const int kx = s / 3, ky = s - 3 * kx;   // order == original kx-outer/ky-inner
            // prefetch B for next tap (crosses into chunk 1 at the end of chunk 0)
            {
                int s2 = s + 1;
                if (s2 < 9)      loadB((s2 - (s2 / 3) * 3) * 3 + s2 / 3, c, bnxt);
                else if (c == 0) loadB(0, 1, bnxt);
            }
            V32 a2[2];
            #pragma unroll
            for (int f = 0; f < 2; ++f) {
                int cell = (2 * w + ky + f) * 34 + l31 + kx;
                a2[f].q[0] = *(const uint4v*)(s_a + (2 * kh)     * SAPL_Q + cell * 16);
                a2[f].q[1] = *(const uint4v*)(s_a + (2 * kh + 1) * SAPL_Q + cell * 16);
            }
            #pragma unroll
            for (int mt = 0; mt < 2; ++mt) {
                acc[mt][0] = __builtin_amdgcn_mfma_scale_f32_32x32x64_f8f6f4(
                    a2[mt].v, bcur[0].v, acc[mt][0], 0, 0, 0, 127, 0, 127);
                acc[mt][1] = __builtin_amdgcn_mfma_scale_f32_32x32x64_f8f6f4(
                    a2[mt].v, bcur[1].v, acc[mt][1], 0, 0, 0, 127, 0, 127);
            }
            bcur[0] = bnxt[0];
            bcur[1] = bnxt[1];
        }
    }

    // ---- epilogue: h = acc/64 + b1, relu -> s_h (bf16, 8 planes of 8 oc) ----
    __syncthreads();
    #pragma unroll
    for (int nt = 0; nt < 2; ++nt) {
        float bias = b1[g * 64 + nt * 32 + l31];
        int plane = nt * 4 + (l31 >> 3);
        #pragma unroll
        for (int mt = 0; mt < 2; ++mt) {
            int lr = 2 * w + mt;
            #pragma unroll
            for (int reg = 0; reg < 16; ++reg) {
                int col = (reg & 3) + 8 * (reg >> 2) + 4 * kh;   // C layout: m = crop col
                float hv = fmaxf(fmaf(acc[mt][nt][reg], 0.015625f, bias), 0.0f);
                *(ushort_t*)(smem + plane * PSTR_Q + ((lr * 32 + col) * 8 + (l31 & 7)) * 2) = f2bf(hv);
            }
        }
    }
    __syncthreads();

    // ---- v_tap = h @ W2^T (bf16, K=64 oc over 4 x K16) ----
    floatx16 vacc[2];
    #pragma unroll
    for (int mt = 0; mt < 2; ++mt)
        #pragma unroll
        for (int r = 0; r < 16; ++r) vacc[mt][r] = 0.0f;
    #pragma unroll
    for (int ks = 0; ks < 4; ++ks) {
        short8 bw = *(const short8*)&w2r[l31 * 256 + g * 64 + ks * 16 + kh * 8];
        #pragma unroll
        for (int mt = 0; mt < 2; ++mt) {
            short8 ah = *(const short8*)(smem + (ks * 2 + kh) * PSTR_Q + ((2 * w + mt) * 32 + l31) * 16);
            vacc[mt] = __builtin_amdgcn_mfma_f32_32x32x16_bf16(ah, bw, vacc[mt], 0, 0, 0);
        }
    }

    // ---- scatter v_tap into 10x32 tile (s_h now dead -> union), then global atomics ----
    __syncthreads();
    float* s_log = (float*)smem;
    for (int i = t; i < 320; i += 256) s_log[i] = 0.0f;
    __syncthreads();
    if (l31 < 9) {
        int ky = l31 / 3, kx = l31 - ky * 3;
        #pragma unroll
        for (int mt = 0; mt < 2; ++mt) {
            int outr = 2 * w + mt + 2 - ky;       // tile row; R = r0 + outr - 1
            #pragma unroll
            for (int reg = 0; reg < 16; ++reg) {
                int col  = (reg & 3) + 8 * (reg >> 2) + 4 * kh;
                int outc = col + 1 - kx;
                if (outc >= 0 && outc < 32)
                    atomicAdd(&s_log[outr * 32 + outc], vacc[mt][reg]);
            }
        }
    }
    __syncthreads();
    for (int i = t; i < 320; i += 256) {
        int outr = i >> 5, outc = i & 31;
        int R = r0 + outr - 1;
        if ((unsigned)R < 32u)
            atomicAdd(&logits[n * 1024 + R * 32 + outc], s_log[i]);
    }
}

__global__ __launch_bounds__(256) void bce_reduce_kernel(
    const float* __restrict__ logits, const int* __restrict__ seg,
    const int* __restrict__ anchors, const int* __restrict__ labels,
    const int* __restrict__ base_classes, const float* __restrict__ b2,
    float* __restrict__ out)
{
    const int n = blockIdx.x;
    const int t = threadIdx.x;
    const int y0 = anchors[n * 4 + 2];
    const int x0 = anchors[n * 4 + 0];
    const int tgt_cls = base_classes[labels[n]];
    const float bias2 = b2[0];

    float lsum = 0.0f;
    #pragma unroll
    for (int r = 0; r < 4; ++r) {
        int p = t + r * 256;
        int i = p >> 5, j = p & 31;
        float l = logits[n * 1024 + p] + bias2;
        int sv = seg[(size_t)(4 * (y0 + i)) * IMGD + 4 * (x0 + j)];
        float tgt = (sv == tgt_cls) ? 1.0f : 0.0f;
        lsum += fmaxf(l, 0.0f) - l * tgt + log1pf(expf(-fabsf(l)));
    }
    #pragma unroll
    for (int off = 32; off > 0; off >>= 1) lsum += __shfl_down(lsum, off, 64);
    __shared__ float s[4];
    if ((t & 63) == 0) s[t >> 6] = lsum;
    __syncthreads();
    if (t == 0) {
        float tot = s[0] + s[1] + s[2] + s[3];
        const float scale = 1.0f / (1024.0f * (256.0f + 1e-10f));
        atomicAdd(out, tot * scale);
    }
}

extern "C" void kernel_launch(void* const* d_in, const int* in_sizes, int n_in,
                              void* d_out, int out_size, void* d_ws, size_t ws_size,
                              hipStream_t stream) {
    const float* fm           = (const float*)d_in[0];
    const int*   seg          = (const int*)d_in[1];
    const int*   anchors      = (const int*)d_in[2];
    const int*   labels       = (const int*)d_in[3];
    const int*   base_classes = (const int*)d_in[4];
    const float* W1           = (const float*)d_in[5];
    const float* b1           = (const float*)d_in[6];
    const float* W2           = (const float*)d_in[7];
    const float* b2           = (const float*)d_in[8];
    float* out = (float*)d_out;

    float*    logits = (float*)d_ws;
    uchar_t*  w1b    = (uchar_t*)((char*)d_ws + W1R_BYTE_OFF);
    ushort_t* w2r    = (ushort_t*)((char*)d_ws + W2R_BYTE_OFF);
    uchar_t*  fmT    = (uchar_t*)((char*)d_ws + FMT_BYTE_OFF);

    prep_misc<<<1024 + 128 + 1, 256, 0, stream>>>(W1, W2, logits, out, w1b, w2r);
    prep_transpose<<<dim3(10, 320), 256, 0, stream>>>(fm, fmT);
    conv_mfma_kernel<<<4096, 256, 0, stream>>>(anchors, fmT, w1b, w2r, b1, logits);
    bce_reduce_kernel<<<NA, 256, 0, stream>>>(logits, seg, anchors, labels, base_classes, b2, out);
}